// Round 4
// baseline (936.499 us; speedup 1.0000x reference)
//
#include <hip/hip_runtime.h>
#include <hip/hip_bf16.h>

#define B_   2048
#define L_   200
#define DM_  512
#define HID_ 256
#define V_   40000
#define NPAD 40064          // 313 * 128
#define LN_EPS 1e-5f

typedef short bf16x8 __attribute__((ext_vector_type(8)));
typedef float f32x4  __attribute__((ext_vector_type(4)));

#define GLOAD_LDS16(g, l)                                                     \
    __builtin_amdgcn_global_load_lds(                                         \
        (const __attribute__((address_space(1))) void*)(g),                   \
        (__attribute__((address_space(3))) void*)(l), 16, 0, 0)

// ---------------------------------------------------------------------------
// Kernel 1: W2 (f32, [256][40000]) -> WT (bf16, [NPAD][256])  (unchanged)
// ---------------------------------------------------------------------------
__global__ __launch_bounds__(256) void transpose_w2(const float* __restrict__ W2,
                                                    __hip_bfloat16* __restrict__ WT) {
    __shared__ float tile[64][65];
    const int n0 = blockIdx.x * 64;
    const int k0 = blockIdx.y * 64;
    const int tid = threadIdx.x;

    const int c = tid & 63, r4 = tid >> 6;
#pragma unroll
    for (int p = 0; p < 16; ++p) {
        int r = p * 4 + r4;
        int n = n0 + c;
        tile[r][c] = (n < V_) ? W2[(size_t)(k0 + r) * V_ + n] : 0.f;
    }
    __syncthreads();

    const int nl = tid >> 3;
    const int kb = (tid & 7) * 8;
#pragma unroll
    for (int p = 0; p < 2; ++p) {
        int n = p * 32 + nl;
        bf16x8 v;
#pragma unroll
        for (int j = 0; j < 8; ++j) {
            __hip_bfloat16 h = __float2bfloat16(tile[kb + j][n]);
            v[j] = *(short*)&h;
        }
        *(bf16x8*)(WT + (size_t)(n0 + n) * HID_ + k0 + kb) = v;
    }
}

// ---------------------------------------------------------------------------
// Kernel 2: head (unchanged)
// ---------------------------------------------------------------------------
__global__ __launch_bounds__(512) void head_kernel(const float* __restrict__ hidden,
                                                   const float* __restrict__ W1,
                                                   const float* __restrict__ b1,
                                                   const float* __restrict__ gamma,
                                                   const float* __restrict__ beta,
                                                   __hip_bfloat16* __restrict__ hout) {
    __shared__ float hid[8][DM_];
    __shared__ float part[8][HID_];
    __shared__ float red[2][8][4];
    const int r0 = blockIdx.x * 8;
    const int tid = threadIdx.x;
    const int col = tid & 255, half = tid >> 8;

    {
        const float4* src = (const float4*)(hidden + (size_t)r0 * DM_);
        float4* dst = (float4*)(&hid[0][0]);
        for (int i = tid; i < 8 * DM_ / 4; i += 512) dst[i] = src[i];
    }
    __syncthreads();

    float acc[8] = {0.f, 0.f, 0.f, 0.f, 0.f, 0.f, 0.f, 0.f};
    const int kbeg = half * (DM_ / 2);
#pragma unroll 8
    for (int k = kbeg; k < kbeg + DM_ / 2; ++k) {
        float w = W1[(size_t)k * HID_ + col];
#pragma unroll
        for (int r = 0; r < 8; ++r) acc[r] = fmaf(hid[r][k], w, acc[r]);
    }

    if (half == 1) {
#pragma unroll
        for (int r = 0; r < 8; ++r) part[r][col] = acc[r];
    }
    __syncthreads();
    if (half == 0) {
        const float b1v = b1[col], gv = gamma[col], bev = beta[col];
        const int lane = col & 63, wv = col >> 6;
        float v[8];
#pragma unroll
        for (int r = 0; r < 8; ++r) {
            v[r] = acc[r] + part[r][col] + b1v;
            float s = v[r], q = v[r] * v[r];
#pragma unroll
            for (int off = 1; off < 64; off <<= 1) {
                s += __shfl_xor(s, off);
                q += __shfl_xor(q, off);
            }
            if (lane == 0) { red[0][r][wv] = s; red[1][r][wv] = q; }
        }
        __syncthreads();
#pragma unroll
        for (int r = 0; r < 8; ++r) {
            float s  = red[0][r][0] + red[0][r][1] + red[0][r][2] + red[0][r][3];
            float q  = red[1][r][0] + red[1][r][1] + red[1][r][2] + red[1][r][3];
            float mu = s * (1.f / HID_);
            float var = q * (1.f / HID_) - mu * mu;
            float hn = (v[r] - mu) * rsqrtf(var + LN_EPS) * gv + bev;
            float g  = 0.5f * hn * (1.f + erff(hn * 0.70710678118654752f));
            hout[(size_t)(r0 + r) * HID_ + col] = __float2bfloat16(g);
        }
    }
}

// ---------------------------------------------------------------------------
// Kernel 3: GEMM — whole-K LDS stage (128 KB), single barrier, XCD-affinity
// tile remap, C^T operand swap for coalesced float4 epilogue.
// gridDim.z = replication for rocprof visibility (byte-identical writes).
// ---------------------------------------------------------------------------
#define BM 128
#define BN 128

__global__ __launch_bounds__(256, 1) void gemm_kernel(const __hip_bfloat16* __restrict__ hA,
                                                      const __hip_bfloat16* __restrict__ BT,
                                                      const float* __restrict__ b2,
                                                      const float* __restrict__ lsp,
                                                      float* __restrict__ out) {
    __shared__ __hip_bfloat16 As[BM * HID_];   // 64 KB
    __shared__ __hip_bfloat16 Bs[BN * HID_];   // 64 KB

    // XCD-affinity remap: all 16 row-blocks of a col-tile share g%8 (one XCD).
    const int g = blockIdx.x;
    const int G = g >> 7, ii = g & 127;
    int rt, ct;
    if (G < 39) { ct = G * 8 + (ii & 7); rt = ii >> 3; }   // 8 col-tiles/group
    else        { ct = 312;              rt = ii & 15; }   // remainder tile
    const int r0 = rt * BM, c0 = ct * BN;

    const int tid = threadIdx.x;
    const int lane = tid & 63;
    const int wv = tid >> 6;
    const int wr = (wv >> 1) * 64;
    const int wc = (wv & 1) * 64;
    const float ls = lsp[0];

    // ---- stage ALL of K: 64 chunks of 1KB each per matrix, wave wv owns 16.
    // LDS linear; source pre-swizzled: LDS[row][chunk c] holds global chunk
    // c ^ (row&7)  (chunk = 8 bf16 = 16B; row stride = 256 bf16 = 512B).
    {
        const __hip_bfloat16* aB = hA + (size_t)r0 * HID_;
        const __hip_bfloat16* bB = BT + (size_t)c0 * HID_;
        const int cc = lane & 31;            // chunk col within row
        const int rhalf = lane >> 5;         // which of the 2 rows in a 1KB chunk
#pragma unroll
        for (int i = 0; i < 16; ++i) {
            const int ch = wv * 16 + i;      // 0..63
            const int r = ch * 2 + rhalf;    // tile row
            const int csrc = cc ^ (r & 7);
            GLOAD_LDS16(aB + (size_t)r * HID_ + csrc * 8, (char*)As + ch * 1024);
            GLOAD_LDS16(bB + (size_t)r * HID_ + csrc * 8, (char*)Bs + ch * 1024);
        }
    }
    __syncthreads();

    f32x4 acc[4][4];
#pragma unroll
    for (int m = 0; m < 4; ++m)
#pragma unroll
        for (int n = 0; n < 4; ++n) acc[m][n] = (f32x4){0.f, 0.f, 0.f, 0.f};

    const int rb = wr + (lane & 15);
    const int cb = wc + (lane & 15);
#pragma unroll
    for (int ks = 0; ks < HID_ / 32; ++ks) {
        const int kb = ks * 32 + ((lane >> 4) << 3);
        const int ke = kb ^ ((lane & 7) << 3);           // swizzled read
        bf16x8 af[4], bf[4];
#pragma unroll
        for (int m = 0; m < 4; ++m)
            af[m] = *(const bf16x8*)(As + (size_t)(rb + m * 16) * HID_ + ke);
#pragma unroll
        for (int n = 0; n < 4; ++n)
            bf[n] = *(const bf16x8*)(Bs + (size_t)(cb + n * 16) * HID_ + ke);
#pragma unroll
        for (int m = 0; m < 4; ++m)
#pragma unroll
            for (int n = 0; n < 4; ++n)
                acc[m][n] = __builtin_amdgcn_mfma_f32_16x16x32_bf16(
                    bf[n], af[m], acc[m][n], 0, 0, 0);   // swapped -> C^T
    }

    // epilogue: lane holds 4 consecutive out cols per frag -> float4 stores
    const int orow = r0 + wr + (lane & 15);
    const int ocol = c0 + wc + ((lane >> 4) << 2);
    float4 b2v[4];
#pragma unroll
    for (int n = 0; n < 4; ++n) {
        int col = ocol + n * 16;
        b2v[n] = (col < V_) ? *(const float4*)(b2 + col)
                            : (float4){0.f, 0.f, 0.f, 0.f};
    }
#pragma unroll
    for (int m = 0; m < 4; ++m) {
        float* orp = out + (size_t)(orow + m * 16) * V_;
#pragma unroll
        for (int n = 0; n < 4; ++n) {
            int col = ocol + n * 16;
            if (col < V_) {
                float4 o;
                o.x = (acc[m][n][0] + b2v[n].x) * ls;
                o.y = (acc[m][n][1] + b2v[n].y) * ls;
                o.z = (acc[m][n][2] + b2v[n].z) * ls;
                o.w = (acc[m][n][3] + b2v[n].w) * ls;
                *(float4*)(orp + col) = o;
            }
        }
    }
}

// ---------------------------------------------------------------------------
// Kernel 4: history scatter (unchanged)
// ---------------------------------------------------------------------------
__global__ __launch_bounds__(256) void hist_kernel(const int* __restrict__ loc,
                                                   const int* __restrict__ mask,
                                                   const float* __restrict__ rw,
                                                   const float* __restrict__ fw,
                                                   const float* __restrict__ hs,
                                                   float* __restrict__ out) {
    const int idx = blockIdx.x * 256 + threadIdx.x;
    if (idx >= B_ * L_) return;
    const int b = idx / L_, t = idx - b * L_;
    if (mask[idx] != 0) {
        float recency = expf(-0.1f * (float)(L_ - 1 - t)) * rw[0];
        float val = (recency + fw[0]) * hs[0];
        atomicAdd(out + (size_t)b * V_ + loc[idx], val);
    }
}

// ---------------------------------------------------------------------------
// MEASUREMENT: gemm replicated via gridDim.z=5 (identical writes, benign).
//   T_gemm = (dur - 60.8) / 5.  Per-dispatch ~5*T_gemm -> visible in top-5.
// ---------------------------------------------------------------------------
extern "C" void kernel_launch(void* const* d_in, const int* in_sizes, int n_in,
                              void* d_out, int out_size, void* d_ws, size_t ws_size,
                              hipStream_t stream) {
    const float* hidden = (const float*)d_in[0];
    const int*   loc    = (const int*)d_in[1];
    const int*   mask   = (const int*)d_in[2];
    const float* W1     = (const float*)d_in[3];
    const float* b1     = (const float*)d_in[4];
    const float* gamma  = (const float*)d_in[5];
    const float* beta   = (const float*)d_in[6];
    const float* W2     = (const float*)d_in[7];
    const float* b2     = (const float*)d_in[8];
    const float* rw     = (const float*)d_in[9];
    const float* fw     = (const float*)d_in[10];
    const float* hs     = (const float*)d_in[11];
    const float* ls     = (const float*)d_in[12];
    float* out = (float*)d_out;

    __hip_bfloat16* WT   = (__hip_bfloat16*)d_ws;
    __hip_bfloat16* hbuf = (__hip_bfloat16*)((char*)d_ws + 20512768);

    transpose_w2<<<dim3(NPAD / 64, HID_ / 64), 256, 0, stream>>>(W2, WT);
    head_kernel<<<B_ / 8, 512, 0, stream>>>(hidden, W1, b1, gamma, beta, hbuf);
    gemm_kernel<<<dim3((B_ / BM) * (NPAD / BN), 1, 5), 256, 0, stream>>>(hbuf, WT, b2, ls, out);
    hist_kernel<<<(B_ * L_ + 255) / 256, 256, 0, stream>>>(loc, mask, rw, fw, hs, out);
}

// Round 6
// 203.565 us; speedup vs baseline: 4.6005x; 4.6005x over previous
//
#include <hip/hip_runtime.h>
#include <hip/hip_bf16.h>

#define B_   2048
#define L_   200
#define DM_  512
#define HID_ 256
#define V_   40000
#define NPAD 40064          // 313 * 128
#define LN_EPS 1e-5f

typedef short bf16x8 __attribute__((ext_vector_type(8)));
typedef float f32x4  __attribute__((ext_vector_type(4)));

#define GLOAD_LDS16(g, l)                                                     \
    __builtin_amdgcn_global_load_lds(                                         \
        (const __attribute__((address_space(1))) void*)(g),                   \
        (__attribute__((address_space(3))) void*)(l), 16, 0, 0)

// ---------------------------------------------------------------------------
// Kernel 1: W2 (f32, [256][40000]) -> WT (bf16, [NPAD][256])  (unchanged)
// ---------------------------------------------------------------------------
__global__ __launch_bounds__(256) void transpose_w2(const float* __restrict__ W2,
                                                    __hip_bfloat16* __restrict__ WT) {
    __shared__ float tile[64][65];
    const int n0 = blockIdx.x * 64;
    const int k0 = blockIdx.y * 64;
    const int tid = threadIdx.x;

    const int c = tid & 63, r4 = tid >> 6;
#pragma unroll
    for (int p = 0; p < 16; ++p) {
        int r = p * 4 + r4;
        int n = n0 + c;
        tile[r][c] = (n < V_) ? W2[(size_t)(k0 + r) * V_ + n] : 0.f;
    }
    __syncthreads();

    const int nl = tid >> 3;
    const int kb = (tid & 7) * 8;
#pragma unroll
    for (int p = 0; p < 2; ++p) {
        int n = p * 32 + nl;
        bf16x8 v;
#pragma unroll
        for (int j = 0; j < 8; ++j) {
            __hip_bfloat16 h = __float2bfloat16(tile[kb + j][n]);
            v[j] = *(short*)&h;
        }
        *(bf16x8*)(WT + (size_t)(n0 + n) * HID_ + k0 + kb) = v;
    }
}

// ---------------------------------------------------------------------------
// Kernel 2: head (unchanged)
// ---------------------------------------------------------------------------
__global__ __launch_bounds__(512) void head_kernel(const float* __restrict__ hidden,
                                                   const float* __restrict__ W1,
                                                   const float* __restrict__ b1,
                                                   const float* __restrict__ gamma,
                                                   const float* __restrict__ beta,
                                                   __hip_bfloat16* __restrict__ hout) {
    __shared__ float hid[8][DM_];
    __shared__ float part[8][HID_];
    __shared__ float red[2][8][4];
    const int r0 = blockIdx.x * 8;
    const int tid = threadIdx.x;
    const int col = tid & 255, half = tid >> 8;

    {
        const float4* src = (const float4*)(hidden + (size_t)r0 * DM_);
        float4* dst = (float4*)(&hid[0][0]);
        for (int i = tid; i < 8 * DM_ / 4; i += 512) dst[i] = src[i];
    }
    __syncthreads();

    float acc[8] = {0.f, 0.f, 0.f, 0.f, 0.f, 0.f, 0.f, 0.f};
    const int kbeg = half * (DM_ / 2);
#pragma unroll 8
    for (int k = kbeg; k < kbeg + DM_ / 2; ++k) {
        float w = W1[(size_t)k * HID_ + col];
#pragma unroll
        for (int r = 0; r < 8; ++r) acc[r] = fmaf(hid[r][k], w, acc[r]);
    }

    if (half == 1) {
#pragma unroll
        for (int r = 0; r < 8; ++r) part[r][col] = acc[r];
    }
    __syncthreads();
    if (half == 0) {
        const float b1v = b1[col], gv = gamma[col], bev = beta[col];
        const int lane = col & 63, wv = col >> 6;
        float v[8];
#pragma unroll
        for (int r = 0; r < 8; ++r) {
            v[r] = acc[r] + part[r][col] + b1v;
            float s = v[r], q = v[r] * v[r];
#pragma unroll
            for (int off = 1; off < 64; off <<= 1) {
                s += __shfl_xor(s, off);
                q += __shfl_xor(q, off);
            }
            if (lane == 0) { red[0][r][wv] = s; red[1][r][wv] = q; }
        }
        __syncthreads();
#pragma unroll
        for (int r = 0; r < 8; ++r) {
            float s  = red[0][r][0] + red[0][r][1] + red[0][r][2] + red[0][r][3];
            float q  = red[1][r][0] + red[1][r][1] + red[1][r][2] + red[1][r][3];
            float mu = s * (1.f / HID_);
            float var = q * (1.f / HID_) - mu * mu;
            float hn = (v[r] - mu) * rsqrtf(var + LN_EPS) * gv + bev;
            float g  = 0.5f * hn * (1.f + erff(hn * 0.70710678118654752f));
            hout[(size_t)(r0 + r) * HID_ + col] = __float2bfloat16(g);
        }
    }
}

// ---------------------------------------------------------------------------
// Kernel 3: GEMM — whole-K LDS (128 KB), single stage barrier, XCD-affinity
// remap, C^T operand swap, NONTEMPORAL f32x4 epilogue stores.
// ---------------------------------------------------------------------------
#define BM 128
#define BN 128

__global__ __launch_bounds__(256, 1) void gemm_kernel(const __hip_bfloat16* __restrict__ hA,
                                                      const __hip_bfloat16* __restrict__ BT,
                                                      const float* __restrict__ b2,
                                                      const float* __restrict__ lsp,
                                                      float* __restrict__ out) {
    __shared__ __hip_bfloat16 As[BM * HID_];   // 64 KB
    __shared__ __hip_bfloat16 Bs[BN * HID_];   // 64 KB

    const int g = blockIdx.x;
    const int G = g >> 7, ii = g & 127;
    int rt, ct;
    if (G < 39) { ct = G * 8 + (ii & 7); rt = ii >> 3; }
    else        { ct = 312;              rt = ii & 15; }
    const int r0 = rt * BM, c0 = ct * BN;

    const int tid = threadIdx.x;
    const int lane = tid & 63;
    const int wv = tid >> 6;
    const int wr = (wv >> 1) * 64;
    const int wc = (wv & 1) * 64;
    const float ls = lsp[0];

    // stage ALL of K; LDS linear, source pre-swizzled (chunk c ^ (row&7))
    {
        const __hip_bfloat16* aB = hA + (size_t)r0 * HID_;
        const __hip_bfloat16* bB = BT + (size_t)c0 * HID_;
        const int cc = lane & 31;
        const int rhalf = lane >> 5;
#pragma unroll
        for (int i = 0; i < 16; ++i) {
            const int ch = wv * 16 + i;
            const int r = ch * 2 + rhalf;
            const int csrc = cc ^ (r & 7);
            GLOAD_LDS16(aB + (size_t)r * HID_ + csrc * 8, (char*)As + ch * 1024);
            GLOAD_LDS16(bB + (size_t)r * HID_ + csrc * 8, (char*)Bs + ch * 1024);
        }
    }
    __syncthreads();

    f32x4 acc[4][4];
#pragma unroll
    for (int m = 0; m < 4; ++m)
#pragma unroll
        for (int n = 0; n < 4; ++n) acc[m][n] = (f32x4){0.f, 0.f, 0.f, 0.f};

    const int rb = wr + (lane & 15);
    const int cb = wc + (lane & 15);
#pragma unroll
    for (int ks = 0; ks < HID_ / 32; ++ks) {
        const int kb = ks * 32 + ((lane >> 4) << 3);
        const int ke = kb ^ ((lane & 7) << 3);
        bf16x8 af[4], bf[4];
#pragma unroll
        for (int m = 0; m < 4; ++m)
            af[m] = *(const bf16x8*)(As + (size_t)(rb + m * 16) * HID_ + ke);
#pragma unroll
        for (int n = 0; n < 4; ++n)
            bf[n] = *(const bf16x8*)(Bs + (size_t)(cb + n * 16) * HID_ + ke);
#pragma unroll
        for (int m = 0; m < 4; ++m)
#pragma unroll
            for (int n = 0; n < 4; ++n)
                acc[m][n] = __builtin_amdgcn_mfma_f32_16x16x32_bf16(
                    bf[n], af[m], acc[m][n], 0, 0, 0);
    }

    // epilogue: nontemporal coalesced f32x4 stores
    const int orow = r0 + wr + (lane & 15);
    const int ocol = c0 + wc + ((lane >> 4) << 2);
    f32x4 b2v[4];
#pragma unroll
    for (int n = 0; n < 4; ++n) {
        int col = ocol + n * 16;
        b2v[n] = (col < V_) ? *(const f32x4*)(b2 + col)
                            : (f32x4){0.f, 0.f, 0.f, 0.f};
    }
#pragma unroll
    for (int m = 0; m < 4; ++m) {
        float* orp = out + (size_t)(orow + m * 16) * V_;
#pragma unroll
        for (int n = 0; n < 4; ++n) {
            int col = ocol + n * 16;
            if (col < V_) {
                f32x4 o = (acc[m][n] + b2v[n]) * ls;
                __builtin_nontemporal_store(o, (f32x4*)(orp + col));
            }
        }
    }
}

// ---------------------------------------------------------------------------
// Kernel 4: history scatter (unchanged)
// ---------------------------------------------------------------------------
__global__ __launch_bounds__(256) void hist_kernel(const int* __restrict__ loc,
                                                   const int* __restrict__ mask,
                                                   const float* __restrict__ rw,
                                                   const float* __restrict__ fw,
                                                   const float* __restrict__ hs,
                                                   float* __restrict__ out) {
    const int idx = blockIdx.x * 256 + threadIdx.x;
    if (idx >= B_ * L_) return;
    const int b = idx / L_, t = idx - b * L_;
    if (mask[idx] != 0) {
        float recency = expf(-0.1f * (float)(L_ - 1 - t)) * rw[0];
        float val = (recency + fw[0]) * hs[0];
        atomicAdd(out + (size_t)b * V_ + loc[idx], val);
    }
}

// ---------------------------------------------------------------------------
extern "C" void kernel_launch(void* const* d_in, const int* in_sizes, int n_in,
                              void* d_out, int out_size, void* d_ws, size_t ws_size,
                              hipStream_t stream) {
    const float* hidden = (const float*)d_in[0];
    const int*   loc    = (const int*)d_in[1];
    const int*   mask   = (const int*)d_in[2];
    const float* W1     = (const float*)d_in[3];
    const float* b1     = (const float*)d_in[4];
    const float* gamma  = (const float*)d_in[5];
    const float* beta   = (const float*)d_in[6];
    const float* W2     = (const float*)d_in[7];
    const float* b2     = (const float*)d_in[8];
    const float* rw     = (const float*)d_in[9];
    const float* fw     = (const float*)d_in[10];
    const float* hs     = (const float*)d_in[11];
    const float* ls     = (const float*)d_in[12];
    float* out = (float*)d_out;

    __hip_bfloat16* WT   = (__hip_bfloat16*)d_ws;
    __hip_bfloat16* hbuf = (__hip_bfloat16*)((char*)d_ws + 20512768);

    transpose_w2<<<dim3(NPAD / 64, HID_ / 64), 256, 0, stream>>>(W2, WT);
    head_kernel<<<B_ / 8, 512, 0, stream>>>(hidden, W1, b1, gamma, beta, hbuf);
    gemm_kernel<<<(B_ / BM) * (NPAD / BN), 256, 0, stream>>>(hbuf, WT, b2, ls, out);
    hist_kernel<<<(B_ * L_ + 255) / 256, 256, 0, stream>>>(loc, mask, rw, fw, hs, out);
}